// Round 9
// baseline (663.778 us; speedup 1.0000x reference)
//
#include <hip/hip_runtime.h>

#define N_NODES 50000
#define F_IN 500
#define F_HID 128
#define F_OUT 16
#define NSCAN_BLKS ((N_NODES + 255) / 256)   // 196

// ---------------- bf16 helpers (RTNE pack, shift decode) ----------------

__device__ __forceinline__ unsigned bf16_pack2(float a, float b) {
    unsigned ua = __float_as_uint(a);
    unsigned ub = __float_as_uint(b);
    ua = (ua + 0x7fffu + ((ua >> 16) & 1u)) >> 16;
    ub = (ub + 0x7fffu + ((ub >> 16) & 1u)) >> 16;
    return ua | (ub << 16);
}
__device__ __forceinline__ float bf_lo(unsigned v) { return __uint_as_float(v << 16); }
__device__ __forceinline__ float bf_hi(unsigned v) { return __uint_as_float(v & 0xffff0000u); }

// ---------------- CSR build (single atomic pass) ----------------

// one pass: histogram + per-edge rank (claim order within destination)
__global__ void k_hist_rank(const int* __restrict__ dst, int* __restrict__ hist,
                            int* __restrict__ rank, int E) {
    int e = blockIdx.x * 256 + threadIdx.x;
    if (e < E) rank[e] = atomicAdd(&hist[dst[e]], 1);
}

__global__ __launch_bounds__(256) void k_scan_local(const int* __restrict__ hist,
                                                    int* __restrict__ rowptr,
                                                    int* __restrict__ blksum) {
    __shared__ int s[256];
    const int tid = threadIdx.x;
    const int i = blockIdx.x * 256 + tid;
    int v = (i < N_NODES) ? hist[i] : 0;
    s[tid] = v;
    __syncthreads();
#pragma unroll
    for (int ofs = 1; ofs < 256; ofs <<= 1) {
        int t = (tid >= ofs) ? s[tid - ofs] : 0;
        __syncthreads();
        if (tid >= ofs) s[tid] += t;
        __syncthreads();
    }
    if (i < N_NODES) rowptr[i] = s[tid] - v;
    if (tid == 255) blksum[blockIdx.x] = s[255];
}

__global__ __launch_bounds__(256) void k_scan_blk(int* __restrict__ blksum) {
    __shared__ int s[256];
    const int tid = threadIdx.x;
    int v = (tid < NSCAN_BLKS) ? blksum[tid] : 0;
    s[tid] = v;
    __syncthreads();
#pragma unroll
    for (int ofs = 1; ofs < 256; ofs <<= 1) {
        int t = (tid >= ofs) ? s[tid - ofs] : 0;
        __syncthreads();
        if (tid >= ofs) s[tid] += t;
        __syncthreads();
    }
    if (tid < NSCAN_BLKS) blksum[tid] = s[tid] - v;
}

__global__ void k_finalize(const int* __restrict__ hist, int* __restrict__ rowptr,
                           const int* __restrict__ blksum, float* __restrict__ isd, int E) {
    int i = blockIdx.x * 256 + threadIdx.x;
    if (i < N_NODES) {
        rowptr[i] = rowptr[i] + blksum[i >> 8];
        isd[i] = rsqrtf((float)(hist[i] + 1));  // +1 self-loop
    }
    if (i == 0) rowptr[N_NODES] = E;
}

// atomic-free placement
__global__ void k_reorder(const int* __restrict__ src, const int* __restrict__ dst,
                          const int* __restrict__ rank, const int* __restrict__ rowptr,
                          int* __restrict__ csr_src, int E) {
    int e = blockIdx.x * 256 + threadIdx.x;
    if (e >= E) return;
    csr_src[rowptr[dst[e]] + rank[e]] = src[e];
}

// ---------------- Wc = Wlin @ W2  [16,128] ----------------

__global__ void k_wc(const float* __restrict__ W2, const float* __restrict__ Wlin,
                     float* __restrict__ Wc) {
    const int c = blockIdx.x;       // 0..15
    const int j = threadIdx.x;      // 0..127
    const float* wl = Wlin + c * 128;
    float acc = 0.f;
#pragma unroll 4
    for (int k = 0; k < 128; ++k) acc += wl[k] * W2[k * 128 + j];
    Wc[c * 128 + j] = acc;
}

// ---------------- GEMM1: hb[M,128](bf16) = A[M,K] @ B[128,K]^T ----------------
// Round-6 structure + distance-2 prefetch: two register sets, tile t+2's global
// loads issued at the top of iteration t -> ~1.3 iterations of latency cover
// (round-8 exposed ~0.6 iters; HBM latency ~900cyc > 576cyc compute phase).
// One barrier per K-tile preserved. Same math/order as round 8.

__global__ __launch_bounds__(256) void gemm1_db_bf16(const float* __restrict__ A,
                                                     const float* __restrict__ B,
                                                     unsigned* __restrict__ hb,  // [M][64] bf16x2
                                                     int M, int K) {
    __shared__ float As[2][16][68];
    __shared__ float Bs[2][16][132];
    const int tid = threadIdx.x;
    const int tx = tid & 15, ty = tid >> 4;
    const int m0 = blockIdx.x << 6;

    const int a_row = tid >> 2;
    const int a_kq  = (tid & 3) << 2;
    const int b_row = tid >> 2;
    const int b_kq  = (tid & 3) << 2;
    const bool a_ok = (m0 + a_row) < M;
    const float* Arow  = A + (size_t)(m0 + a_row) * K;
    const float* Brow0 = B + (size_t)b_row * K;
    const float* Brow1 = B + (size_t)(b_row + 64) * K;

    const float4 z4 = make_float4(0.f, 0.f, 0.f, 0.f);
    float4 ra[2], rb0[2], rb1[2];
    const int nt = (K + 15) >> 4;

#define LOADSET(i, t) { const int k0 = (t) << 4;                                        \
        ra[i]  = (a_ok && k0 + a_kq + 3 < K) ? *(const float4*)(Arow  + k0 + a_kq) : z4; \
        rb0[i] = (k0 + b_kq + 3 < K)         ? *(const float4*)(Brow0 + k0 + b_kq) : z4; \
        rb1[i] = (k0 + b_kq + 3 < K)         ? *(const float4*)(Brow1 + k0 + b_kq) : z4; }

#define STORESET(i) {                                  \
        As[i][a_kq + 0][a_row] = ra[i].x;              \
        As[i][a_kq + 1][a_row] = ra[i].y;              \
        As[i][a_kq + 2][a_row] = ra[i].z;              \
        As[i][a_kq + 3][a_row] = ra[i].w;              \
        Bs[i][b_kq + 0][b_row] = rb0[i].x;             \
        Bs[i][b_kq + 1][b_row] = rb0[i].y;             \
        Bs[i][b_kq + 2][b_row] = rb0[i].z;             \
        Bs[i][b_kq + 3][b_row] = rb0[i].w;             \
        Bs[i][b_kq + 0][b_row + 64] = rb1[i].x;        \
        Bs[i][b_kq + 1][b_row + 64] = rb1[i].y;        \
        Bs[i][b_kq + 2][b_row + 64] = rb1[i].z;        \
        Bs[i][b_kq + 3][b_row + 64] = rb1[i].w; }

    // prologue: tile 0 staged, tile 1 in flight
    LOADSET(0, 0);
    STORESET(0);
    if (nt > 1) LOADSET(1, 1);
    __syncthreads();

    float acc[4][8] = {};

    for (int t = 0; t < nt; ++t) {
        const int i = t & 1;
        if (t + 2 < nt) LOADSET(i, t + 2);   // into the set freed by STORESET(t)

        // compute tile t from LDS[i]
#pragma unroll
        for (int k = 0; k < 16; ++k) {
            const float4 av = *(const float4*)&As[i][k][ty << 2];
            const float4 b0 = *(const float4*)&Bs[i][k][tx << 2];
            const float4 b1 = *(const float4*)&Bs[i][k][64 + (tx << 2)];
            const float ar[4] = {av.x, av.y, av.z, av.w};
            const float bc[8] = {b0.x, b0.y, b0.z, b0.w, b1.x, b1.y, b1.z, b1.w};
#pragma unroll
            for (int r = 0; r < 4; ++r)
#pragma unroll
                for (int c = 0; c < 8; ++c) acc[r][c] += ar[r] * bc[c];
        }

        if (t + 1 < nt) {
            const int j = i ^ 1;
            STORESET(j);          // waits on loads issued ~1.3 iterations ago
            __syncthreads();
        }
    }
#undef LOADSET
#undef STORESET

#pragma unroll
    for (int r = 0; r < 4; ++r) {
        int gm = m0 + (ty << 2) + r;
        if (gm >= M) continue;
        unsigned* crow = hb + (size_t)gm * 64;   // 64 uints = 128 bf16
        uint2 q0 = make_uint2(bf16_pack2(acc[r][0], acc[r][1]),
                              bf16_pack2(acc[r][2], acc[r][3]));
        uint2 q1 = make_uint2(bf16_pack2(acc[r][4], acc[r][5]),
                              bf16_pack2(acc[r][6], acc[r][7]));
        *(uint2*)(crow + (tx << 1))      = q0;
        *(uint2*)(crow + 32 + (tx << 1)) = q1;
    }
}

// ---------------- fused gather + zlin, TWO waves per node ----------------
// Each node's edge list is split between two waves (halves the serial
// dependent-load chain, doubles wave count to 100k); partials combined in LDS.
// Block = 256 thr = 2 nodes x 2 waves. Grid = 25000 (N even -> no guard).

__device__ __forceinline__ void gather_range(const unsigned* __restrict__ hh,
                                             const int* __restrict__ csr_src,
                                             const float* __restrict__ isd,
                                             float si, int lane, int e, int end,
                                             float& accx, float& accy) {
    int s[8], t[8];
    bool have = (e + 8 <= end);
    if (have) {
#pragma unroll
        for (int i = 0; i < 8; ++i) s[i] = csr_src[e + i];
    }
    while (have) {
        unsigned v[8];
        float w[8];
#pragma unroll
        for (int i = 0; i < 8; ++i) v[i] = hh[(size_t)s[i] * 64 + lane];
#pragma unroll
        for (int i = 0; i < 8; ++i) w[i] = isd[s[i]];
        const int ne = e + 8;
        const bool nhave = (ne + 8 <= end);
        if (nhave) {
#pragma unroll
            for (int i = 0; i < 8; ++i) t[i] = csr_src[ne + i];
        }
#pragma unroll
        for (int i = 0; i < 8; ++i) {
            const float wi = w[i] * si;
            accx += wi * bf_lo(v[i]);
            accy += wi * bf_hi(v[i]);
        }
#pragma unroll
        for (int i = 0; i < 8; ++i) s[i] = t[i];
        e = ne;
        have = nhave;
    }
    for (; e < end; ++e) {
        const int ss = csr_src[e];
        const float wi = isd[ss] * si;
        const unsigned v = hh[(size_t)ss * 64 + lane];
        accx += wi * bf_lo(v);
        accy += wi * bf_hi(v);
    }
}

__global__ __launch_bounds__(256) void k_gather_fused2(const unsigned* __restrict__ hh,
                                                       const int* __restrict__ rowptr,
                                                       const int* __restrict__ csr_src,
                                                       const float* __restrict__ isd,
                                                       const float* __restrict__ Wc,
                                                       float* __restrict__ z) {
    __shared__ float2 part[2][64];
    const int tid = threadIdx.x;
    const int lane = tid & 63;
    const int waveid = tid >> 6;         // 0..3
    const int slot = waveid >> 1;        // node slot 0..1
    const int half = waveid & 1;         // 0 = primary, 1 = secondary
    const int node = (blockIdx.x << 1) + slot;   // < 50000 always (grid=25000)

    const float si = isd[node];
    const int e0 = rowptr[node], e1 = rowptr[node + 1];
    const int mid = e0 + ((e1 - e0) >> 1);

    float accx = 0.f, accy = 0.f;
    if (half == 0) {
        const unsigned a = hh[(size_t)node * 64 + lane];   // self-loop
        accx = bf_lo(a) * si * si;
        accy = bf_hi(a) * si * si;
        gather_range(hh, csr_src, isd, si, lane, e0, mid, accx, accy);
    } else {
        gather_range(hh, csr_src, isd, si, lane, mid, e1, accx, accy);
        part[slot][lane] = make_float2(accx, accy);
    }
    __syncthreads();
    if (half == 1) return;

    const float2 pb = part[slot][lane];
    accx += pb.x;
    accy += pb.y;

    // relu + Wc dot + wave reduction
    const float rx = fmaxf(accx, 0.f), ry = fmaxf(accy, 0.f);
    float p[16];
#pragma unroll
    for (int c = 0; c < 16; ++c) {
        const float2 wc = *(const float2*)(Wc + c * 128 + (lane << 1));
        p[c] = rx * wc.x + ry * wc.y;
    }
#pragma unroll
    for (int m = 1; m < 64; m <<= 1) {
#pragma unroll
        for (int c = 0; c < 16; ++c) p[c] += __shfl_xor(p[c], m, 64);
    }
    if (lane == 0) {
        float* zr = z + (size_t)node * 16;
        *(float4*)(zr + 0)  = make_float4(p[0],  p[1],  p[2],  p[3]);
        *(float4*)(zr + 4)  = make_float4(p[4],  p[5],  p[6],  p[7]);
        *(float4*)(zr + 8)  = make_float4(p[8],  p[9],  p[10], p[11]);
        *(float4*)(zr + 12) = make_float4(p[12], p[13], p[14], p[15]);
    }
}

// ---------------- gather (16-wide): 4 threads per node ----------------

__global__ __launch_bounds__(256) void k_gather16(const float4* __restrict__ z4,
                                                  const int* __restrict__ rowptr,
                                                  const int* __restrict__ csr_src,
                                                  const float* __restrict__ isd,
                                                  float4* __restrict__ out4) {
    int t = blockIdx.x * 256 + threadIdx.x;
    int n = t >> 2, q = t & 3;
    if (n >= N_NODES) return;
    const float si = isd[n];
    float4 a = z4[(size_t)n * 4 + q];
    float4 acc;
    acc.x = a.x * si * si; acc.y = a.y * si * si;
    acc.z = a.z * si * si; acc.w = a.w * si * si;
    int e = rowptr[n];
    const int end = rowptr[n + 1];
    for (; e + 4 <= end; e += 4) {
        int s0 = csr_src[e],     s1 = csr_src[e + 1];
        int s2 = csr_src[e + 2], s3 = csr_src[e + 3];
        float w0 = isd[s0] * si, w1 = isd[s1] * si;
        float w2 = isd[s2] * si, w3 = isd[s3] * si;
        float4 v0 = z4[(size_t)s0 * 4 + q];
        float4 v1 = z4[(size_t)s1 * 4 + q];
        float4 v2 = z4[(size_t)s2 * 4 + q];
        float4 v3 = z4[(size_t)s3 * 4 + q];
        acc.x += w0 * v0.x; acc.y += w0 * v0.y; acc.z += w0 * v0.z; acc.w += w0 * v0.w;
        acc.x += w1 * v1.x; acc.y += w1 * v1.y; acc.z += w1 * v1.z; acc.w += w1 * v1.w;
        acc.x += w2 * v2.x; acc.y += w2 * v2.y; acc.z += w2 * v2.z; acc.w += w2 * v2.w;
        acc.x += w3 * v3.x; acc.y += w3 * v3.y; acc.z += w3 * v3.z; acc.w += w3 * v3.w;
    }
    for (; e < end; ++e) {
        int s = csr_src[e];
        float w = isd[s] * si;
        float4 v = z4[(size_t)s * 4 + q];
        acc.x += w * v.x; acc.y += w * v.y; acc.z += w * v.z; acc.w += w * v.w;
    }
    out4[(size_t)n * 4 + q] = acc;
}

// ---------------- fallback (round-1 atomic path, all fp32) ----------------

__global__ void k_deg_init(float* __restrict__ deg) {
    int i = blockIdx.x * 256 + threadIdx.x;
    if (i < N_NODES) deg[i] = 1.0f;
}
__global__ void k_deg_count(const int* __restrict__ dst, float* __restrict__ deg, int E) {
    int e = blockIdx.x * 256 + threadIdx.x;
    if (e < E) atomicAdd(&deg[dst[e]], 1.0f);
}
__global__ void k_rsqrt(float* __restrict__ deg) {
    int i = blockIdx.x * 256 + threadIdx.x;
    if (i < N_NODES) deg[i] = rsqrtf(deg[i]);
}
__global__ void k_agg_init(const float4* __restrict__ h, const float* __restrict__ isd,
                           float4* __restrict__ agg) {
    int t = blockIdx.x * 256 + threadIdx.x;
    if (t < N_NODES * (F_HID / 4)) {
        int row = t >> 5;
        float s = isd[row];
        s = s * s;
        float4 v = h[t];
        v.x *= s; v.y *= s; v.z *= s; v.w *= s;
        agg[t] = v;
    }
}
__global__ void k_scatter(const float4* __restrict__ h, const int* __restrict__ src,
                          const int* __restrict__ dst, const float* __restrict__ isd,
                          float* __restrict__ agg, int E) {
    int t = blockIdx.x * 256 + threadIdx.x;
    int e = t >> 5, q = t & 31;
    if (e >= E) return;
    int s = src[e], d = dst[e];
    float norm = isd[s] * isd[d];
    float4 v = h[(long long)s * 32 + q];
    float* out = agg + (long long)d * F_HID + q * 4;
    atomicAdd(out + 0, v.x * norm);
    atomicAdd(out + 1, v.y * norm);
    atomicAdd(out + 2, v.z * norm);
    atomicAdd(out + 3, v.w * norm);
}
template <int BM, int BN, int BK, int TM, int TN, bool RELU_A>
__global__ __launch_bounds__(256) void gemm_nt(const float* __restrict__ A,
                                               const float* __restrict__ B,
                                               float* __restrict__ C,
                                               int M, int N, int K) {
    __shared__ float As[BK][BM + 1];
    __shared__ float Bs[BK][BN + 1];
    const int tid = threadIdx.x;
    const int NTX = BN / TN;
    const int tx = tid % NTX;
    const int ty = tid / NTX;
    const int m0 = blockIdx.x * BM;
    const int n0 = blockIdx.y * BN;
    float acc[TM][TN] = {};
    for (int k0 = 0; k0 < K; k0 += BK) {
        for (int idx = tid; idx < BM * BK; idx += 256) {
            int m = idx / BK, k = idx % BK;
            int gm = m0 + m;
            float v = (gm < M) ? A[(long long)gm * K + k0 + k] : 0.0f;
            if (RELU_A) v = fmaxf(v, 0.0f);
            As[k][m] = v;
        }
        for (int idx = tid; idx < BN * BK; idx += 256) {
            int n = idx / BK, k = idx % BK;
            int gn = n0 + n;
            Bs[k][n] = (gn < N) ? B[(long long)gn * K + k0 + k] : 0.0f;
        }
        __syncthreads();
        for (int k = 0; k < BK; ++k) {
            float a[TM], b[TN];
#pragma unroll
            for (int r = 0; r < TM; ++r) a[r] = As[k][ty * TM + r];
#pragma unroll
            for (int c = 0; c < TN; ++c) b[c] = Bs[k][c * NTX + tx];
#pragma unroll
            for (int r = 0; r < TM; ++r)
#pragma unroll
                for (int c = 0; c < TN; ++c) acc[r][c] += a[r] * b[c];
        }
        __syncthreads();
    }
#pragma unroll
    for (int r = 0; r < TM; ++r) {
        int gm = m0 + ty * TM + r;
        if (gm >= M) continue;
#pragma unroll
        for (int c = 0; c < TN; ++c) {
            int gn = n0 + c * NTX + tx;
            if (gn < N) C[(long long)gm * N + gn] = acc[r][c];
        }
    }
}
__global__ __launch_bounds__(256) void gemm_lin(const float* __restrict__ A,
                                                const float* __restrict__ W,
                                                float* __restrict__ C, int M) {
    __shared__ float Ws[16][129];
    __shared__ float As[16][129];
    const int tid = threadIdx.x;
    for (int idx = tid; idx < 16 * 128; idx += 256) Ws[idx >> 7][idx & 127] = W[idx];
    const int m0 = blockIdx.x * 16;
    for (int idx = tid; idx < 16 * 128; idx += 256) {
        int r = idx >> 7, k = idx & 127;
        int gm = m0 + r;
        As[r][k] = (gm < M) ? A[(long long)gm * 128 + k] : 0.0f;
    }
    __syncthreads();
    const int tc = tid & 15, tr = tid >> 4;
    float s = 0.f;
#pragma unroll 8
    for (int k = 0; k < 128; ++k) s += As[tr][k] * Ws[tc][k];
    int gm = m0 + tr;
    if (gm < M) C[gm * 16 + tc] = s;
}

// ---------------- launcher ----------------

static inline size_t align256(size_t x) { return (x + 255) & ~(size_t)255; }

extern "C" void kernel_launch(void* const* d_in, const int* in_sizes, int n_in,
                              void* d_out, int out_size, void* d_ws, size_t ws_size,
                              hipStream_t stream) {
    const float* x    = (const float*)d_in[0];
    const int*   ei   = (const int*)d_in[1];
    const float* W1   = (const float*)d_in[2];
    const float* W2   = (const float*)d_in[3];
    const float* Wlin = (const float*)d_in[4];
    float* out = (float*)d_out;

    const int E = in_sizes[1] / 2;
    const int* src = ei;
    const int* dst = ei + E;

    // workspace layout (cursor -> rank[E]; total ~64.6 MB, <= round-2-proven footprint)
    char* ws = (char*)d_ws;
    size_t off = 0;
    float* isd  = (float*)(ws + off); off += align256((size_t)N_NODES * 4);
    float* Wc   = (float*)(ws + off); off += align256(16 * 128 * 4);
    float* bufA = (float*)(ws + off); off += align256((size_t)N_NODES * F_HID * 4);
    float* bufB = (float*)(ws + off); off += align256((size_t)N_NODES * F_HID * 4);
    int*   hist    = (int*)(ws + off); off += align256((size_t)N_NODES * 4);
    int*   rowptr  = (int*)(ws + off); off += align256(((size_t)N_NODES + 1) * 4);
    int*   blksum  = (int*)(ws + off); off += align256(256 * 4);
    int*   csr_src = (int*)(ws + off); off += align256((size_t)E * 4);
    int*   rank    = (int*)(ws + off); off += align256((size_t)E * 4);
    const bool use_csr = (off <= ws_size);

    const int nblk_nodes = NSCAN_BLKS;
    const int nblk_edges = (E + 255) / 256;
    const int mtiles = (N_NODES + 63) / 64;

    if (use_csr) {
        unsigned* hb = (unsigned*)bufB;   // [N][64] packed bf16x2 (12.8 MB)
        float*    z  = bufA;              // [N][16] fp32

        // 1. CSR build + normalization (one atomic pass)
        hipMemsetAsync(hist, 0, (size_t)N_NODES * 4, stream);
        k_hist_rank<<<nblk_edges, 256, 0, stream>>>(dst, hist, rank, E);
        k_scan_local<<<nblk_nodes, 256, 0, stream>>>(hist, rowptr, blksum);
        k_scan_blk<<<1, 256, 0, stream>>>(blksum);
        k_finalize<<<nblk_nodes, 256, 0, stream>>>(hist, rowptr, blksum, isd, E);
        k_reorder<<<nblk_edges, 256, 0, stream>>>(src, dst, rank, rowptr, csr_src, E);
        // 2. Wc = Wlin @ W2
        k_wc<<<16, 128, 0, stream>>>(W2, Wlin, Wc);
        // 3. h1 = x @ W1^T  -> bf16  (distance-2 prefetch)
        gemm1_db_bf16<<<mtiles, 256, 0, stream>>>(x, W1, hb, N_NODES, F_IN);
        // 4+5. z = relu(A_norm * h1) @ Wc^T   (fused, 2 waves/node)
        k_gather_fused2<<<N_NODES / 2, 256, 0, stream>>>(
            hb, rowptr, csr_src, isd, Wc, z);
        // 6. out = A_norm * z
        k_gather16<<<(N_NODES * 4 + 255) / 256, 256, 0, stream>>>(
            (const float4*)z, rowptr, csr_src, isd, (float4*)out);
    } else {
        // fallback: atomic scatter path (fp32)
        const int nblk_feat = (N_NODES * (F_HID / 4) + 255) / 256;
        const int nblk_scatter = (int)(((long long)E * 32 + 255) / 256);
        k_deg_init<<<(N_NODES + 255) / 256, 256, 0, stream>>>(isd);
        k_deg_count<<<nblk_edges, 256, 0, stream>>>(dst, isd, E);
        k_rsqrt<<<(N_NODES + 255) / 256, 256, 0, stream>>>(isd);
        gemm_nt<64, 128, 20, 4, 8, false>
            <<<dim3(mtiles, 1), 256, 0, stream>>>(x, W1, bufA, N_NODES, F_HID, F_IN);
        k_agg_init<<<nblk_feat, 256, 0, stream>>>((const float4*)bufA, isd, (float4*)bufB);
        k_scatter<<<nblk_scatter, 256, 0, stream>>>((const float4*)bufA, src, dst, isd, bufB, E);
        gemm_nt<64, 128, 16, 4, 8, true>
            <<<dim3(mtiles, 1), 256, 0, stream>>>(bufB, W2, bufA, N_NODES, F_HID, F_HID);
        k_agg_init<<<nblk_feat, 256, 0, stream>>>((const float4*)bufA, isd, (float4*)bufB);
        k_scatter<<<nblk_scatter, 256, 0, stream>>>((const float4*)bufA, src, dst, isd, bufB, E);
        gemm_lin<<<(N_NODES + 15) / 16, 256, 0, stream>>>(bufB, Wlin, out, N_NODES);
    }
}

// Round 10
// 517.660 us; speedup vs baseline: 1.2823x; 1.2823x over previous
//
#include <hip/hip_runtime.h>

#define N_NODES 50000
#define F_IN 500
#define F_HID 128
#define F_OUT 16
#define NSCAN_BLKS ((N_NODES + 255) / 256)   // 196

// ---------------- bf16 helpers (RTNE pack, shift decode) ----------------

__device__ __forceinline__ unsigned bf16_pack2(float a, float b) {
    unsigned ua = __float_as_uint(a);
    unsigned ub = __float_as_uint(b);
    ua = (ua + 0x7fffu + ((ua >> 16) & 1u)) >> 16;
    ub = (ub + 0x7fffu + ((ub >> 16) & 1u)) >> 16;
    return ua | (ub << 16);
}
__device__ __forceinline__ float bf_lo(unsigned v) { return __uint_as_float(v << 16); }
__device__ __forceinline__ float bf_hi(unsigned v) { return __uint_as_float(v & 0xffff0000u); }

// ---------------- CSR build (single atomic pass, round-9 proven) ----------------

__global__ void k_hist_rank(const int* __restrict__ dst, int* __restrict__ hist,
                            int* __restrict__ rank, int E) {
    int e = blockIdx.x * 256 + threadIdx.x;
    if (e < E) rank[e] = atomicAdd(&hist[dst[e]], 1);
}

__global__ __launch_bounds__(256) void k_scan_local(const int* __restrict__ hist,
                                                    int* __restrict__ rowptr,
                                                    int* __restrict__ blksum) {
    __shared__ int s[256];
    const int tid = threadIdx.x;
    const int i = blockIdx.x * 256 + tid;
    int v = (i < N_NODES) ? hist[i] : 0;
    s[tid] = v;
    __syncthreads();
#pragma unroll
    for (int ofs = 1; ofs < 256; ofs <<= 1) {
        int t = (tid >= ofs) ? s[tid - ofs] : 0;
        __syncthreads();
        if (tid >= ofs) s[tid] += t;
        __syncthreads();
    }
    if (i < N_NODES) rowptr[i] = s[tid] - v;
    if (tid == 255) blksum[blockIdx.x] = s[255];
}

__global__ __launch_bounds__(256) void k_scan_blk(int* __restrict__ blksum) {
    __shared__ int s[256];
    const int tid = threadIdx.x;
    int v = (tid < NSCAN_BLKS) ? blksum[tid] : 0;
    s[tid] = v;
    __syncthreads();
#pragma unroll
    for (int ofs = 1; ofs < 256; ofs <<= 1) {
        int t = (tid >= ofs) ? s[tid - ofs] : 0;
        __syncthreads();
        if (tid >= ofs) s[tid] += t;
        __syncthreads();
    }
    if (tid < NSCAN_BLKS) blksum[tid] = s[tid] - v;
}

__global__ void k_finalize(const int* __restrict__ hist, int* __restrict__ rowptr,
                           const int* __restrict__ blksum, float* __restrict__ isd, int E) {
    int i = blockIdx.x * 256 + threadIdx.x;
    if (i < N_NODES) {
        rowptr[i] = rowptr[i] + blksum[i >> 8];
        isd[i] = rsqrtf((float)(hist[i] + 1));  // +1 self-loop
    }
    if (i == 0) rowptr[N_NODES] = E;
}

__global__ void k_reorder(const int* __restrict__ src, const int* __restrict__ dst,
                          const int* __restrict__ rank, const int* __restrict__ rowptr,
                          int* __restrict__ csr_src, int E) {
    int e = blockIdx.x * 256 + threadIdx.x;
    if (e >= E) return;
    csr_src[rowptr[dst[e]] + rank[e]] = src[e];
}

// ---------------- Wc = Wlin @ W2  [16,128] ----------------

__global__ void k_wc(const float* __restrict__ W2, const float* __restrict__ Wlin,
                     float* __restrict__ Wc) {
    const int c = blockIdx.x;       // 0..15
    const int j = threadIdx.x;      // 0..127
    const float* wl = Wlin + c * 128;
    float acc = 0.f;
#pragma unroll 4
    for (int k = 0; k < 128; ++k) acc += wl[k] * W2[k * 128 + j];
    Wc[c * 128 + j] = acc;
}

// ---------------- GEMM1: hb[M,128](bf16) = A[M,K] @ B[128,K]^T ----------------
// EXACT round-8 kernel (161 us proven, VGPR 84). Round-9's distance-2 prefetch
// regressed to 306 us: VGPR 84->132 halved occupancy (20%->9%). Reverted.

__global__ __launch_bounds__(256) void gemm1_db_bf16(const float* __restrict__ A,
                                                     const float* __restrict__ B,
                                                     unsigned* __restrict__ hb,  // [M][64] bf16x2
                                                     int M, int K) {
    __shared__ float As[2][16][68];
    __shared__ float Bs[2][16][132];
    const int tid = threadIdx.x;
    const int tx = tid & 15, ty = tid >> 4;
    const int m0 = blockIdx.x << 6;

    const int a_row = tid >> 2;
    const int a_kq  = (tid & 3) << 2;
    const int b_row = tid >> 2;
    const int b_kq  = (tid & 3) << 2;
    const bool a_ok = (m0 + a_row) < M;
    const float* Arow  = A + (size_t)(m0 + a_row) * K;
    const float* Brow0 = B + (size_t)b_row * K;
    const float* Brow1 = B + (size_t)(b_row + 64) * K;

    float4 ra, rb0, rb1;
    const float4 z4 = make_float4(0.f, 0.f, 0.f, 0.f);

    ra  = (a_ok && a_kq + 3 < K) ? *(const float4*)(Arow + a_kq) : z4;
    rb0 = (b_kq + 3 < K) ? *(const float4*)(Brow0 + b_kq) : z4;
    rb1 = (b_kq + 3 < K) ? *(const float4*)(Brow1 + b_kq) : z4;

    float acc[4][8] = {};
    const int nt = (K + 15) >> 4;
    int buf = 0;

    for (int t = 0; t < nt; ++t) {
        As[buf][a_kq + 0][a_row] = ra.x;
        As[buf][a_kq + 1][a_row] = ra.y;
        As[buf][a_kq + 2][a_row] = ra.z;
        As[buf][a_kq + 3][a_row] = ra.w;
        Bs[buf][b_kq + 0][b_row] = rb0.x;
        Bs[buf][b_kq + 1][b_row] = rb0.y;
        Bs[buf][b_kq + 2][b_row] = rb0.z;
        Bs[buf][b_kq + 3][b_row] = rb0.w;
        Bs[buf][b_kq + 0][b_row + 64] = rb1.x;
        Bs[buf][b_kq + 1][b_row + 64] = rb1.y;
        Bs[buf][b_kq + 2][b_row + 64] = rb1.z;
        Bs[buf][b_kq + 3][b_row + 64] = rb1.w;
        __syncthreads();

        if (t + 1 < nt) {
            const int k0 = (t + 1) << 4;
            ra  = (a_ok && k0 + a_kq + 3 < K) ? *(const float4*)(Arow + k0 + a_kq) : z4;
            rb0 = (k0 + b_kq + 3 < K) ? *(const float4*)(Brow0 + k0 + b_kq) : z4;
            rb1 = (k0 + b_kq + 3 < K) ? *(const float4*)(Brow1 + k0 + b_kq) : z4;
        }

#pragma unroll
        for (int k = 0; k < 16; ++k) {
            const float4 av = *(const float4*)&As[buf][k][ty << 2];
            const float4 b0 = *(const float4*)&Bs[buf][k][tx << 2];
            const float4 b1 = *(const float4*)&Bs[buf][k][64 + (tx << 2)];
            const float ar[4] = {av.x, av.y, av.z, av.w};
            const float bc[8] = {b0.x, b0.y, b0.z, b0.w, b1.x, b1.y, b1.z, b1.w};
#pragma unroll
            for (int r = 0; r < 4; ++r)
#pragma unroll
                for (int c = 0; c < 8; ++c) acc[r][c] += ar[r] * bc[c];
        }
        buf ^= 1;
    }

#pragma unroll
    for (int r = 0; r < 4; ++r) {
        int gm = m0 + (ty << 2) + r;
        if (gm >= M) continue;
        unsigned* crow = hb + (size_t)gm * 64;   // 64 uints = 128 bf16
        uint2 q0 = make_uint2(bf16_pack2(acc[r][0], acc[r][1]),
                              bf16_pack2(acc[r][2], acc[r][3]));
        uint2 q1 = make_uint2(bf16_pack2(acc[r][4], acc[r][5]),
                              bf16_pack2(acc[r][6], acc[r][7]));
        *(uint2*)(crow + (tx << 1))      = q0;
        *(uint2*)(crow + 32 + (tx << 1)) = q1;
    }
}

// ---------------- fused gather + zlin, TWO waves per node (round-9 proven) ----------------

__device__ __forceinline__ void gather_range(const unsigned* __restrict__ hh,
                                             const int* __restrict__ csr_src,
                                             const float* __restrict__ isd,
                                             float si, int lane, int e, int end,
                                             float& accx, float& accy) {
    int s[8], t[8];
    bool have = (e + 8 <= end);
    if (have) {
#pragma unroll
        for (int i = 0; i < 8; ++i) s[i] = csr_src[e + i];
    }
    while (have) {
        unsigned v[8];
        float w[8];
#pragma unroll
        for (int i = 0; i < 8; ++i) v[i] = hh[(size_t)s[i] * 64 + lane];
#pragma unroll
        for (int i = 0; i < 8; ++i) w[i] = isd[s[i]];
        const int ne = e + 8;
        const bool nhave = (ne + 8 <= end);
        if (nhave) {
#pragma unroll
            for (int i = 0; i < 8; ++i) t[i] = csr_src[ne + i];
        }
#pragma unroll
        for (int i = 0; i < 8; ++i) {
            const float wi = w[i] * si;
            accx += wi * bf_lo(v[i]);
            accy += wi * bf_hi(v[i]);
        }
#pragma unroll
        for (int i = 0; i < 8; ++i) s[i] = t[i];
        e = ne;
        have = nhave;
    }
    for (; e < end; ++e) {
        const int ss = csr_src[e];
        const float wi = isd[ss] * si;
        const unsigned v = hh[(size_t)ss * 64 + lane];
        accx += wi * bf_lo(v);
        accy += wi * bf_hi(v);
    }
}

__global__ __launch_bounds__(256) void k_gather_fused2(const unsigned* __restrict__ hh,
                                                       const int* __restrict__ rowptr,
                                                       const int* __restrict__ csr_src,
                                                       const float* __restrict__ isd,
                                                       const float* __restrict__ Wc,
                                                       float* __restrict__ z) {
    __shared__ float2 part[2][64];
    const int tid = threadIdx.x;
    const int lane = tid & 63;
    const int waveid = tid >> 6;         // 0..3
    const int slot = waveid >> 1;        // node slot 0..1
    const int half = waveid & 1;         // 0 = primary, 1 = secondary
    const int node = (blockIdx.x << 1) + slot;   // < 50000 always (grid=25000)

    const float si = isd[node];
    const int e0 = rowptr[node], e1 = rowptr[node + 1];
    const int mid = e0 + ((e1 - e0) >> 1);

    float accx = 0.f, accy = 0.f;
    if (half == 0) {
        const unsigned a = hh[(size_t)node * 64 + lane];   // self-loop
        accx = bf_lo(a) * si * si;
        accy = bf_hi(a) * si * si;
        gather_range(hh, csr_src, isd, si, lane, e0, mid, accx, accy);
    } else {
        gather_range(hh, csr_src, isd, si, lane, mid, e1, accx, accy);
        part[slot][lane] = make_float2(accx, accy);
    }
    __syncthreads();
    if (half == 1) return;

    const float2 pb = part[slot][lane];
    accx += pb.x;
    accy += pb.y;

    // relu + Wc dot + wave reduction
    const float rx = fmaxf(accx, 0.f), ry = fmaxf(accy, 0.f);
    float p[16];
#pragma unroll
    for (int c = 0; c < 16; ++c) {
        const float2 wc = *(const float2*)(Wc + c * 128 + (lane << 1));
        p[c] = rx * wc.x + ry * wc.y;
    }
#pragma unroll
    for (int m = 1; m < 64; m <<= 1) {
#pragma unroll
        for (int c = 0; c < 16; ++c) p[c] += __shfl_xor(p[c], m, 64);
    }
    if (lane == 0) {
        float* zr = z + (size_t)node * 16;
        *(float4*)(zr + 0)  = make_float4(p[0],  p[1],  p[2],  p[3]);
        *(float4*)(zr + 4)  = make_float4(p[4],  p[5],  p[6],  p[7]);
        *(float4*)(zr + 8)  = make_float4(p[8],  p[9],  p[10], p[11]);
        *(float4*)(zr + 12) = make_float4(p[12], p[13], p[14], p[15]);
    }
}

// ---------------- gather (16-wide): 4 threads per node ----------------

__global__ __launch_bounds__(256) void k_gather16(const float4* __restrict__ z4,
                                                  const int* __restrict__ rowptr,
                                                  const int* __restrict__ csr_src,
                                                  const float* __restrict__ isd,
                                                  float4* __restrict__ out4) {
    int t = blockIdx.x * 256 + threadIdx.x;
    int n = t >> 2, q = t & 3;
    if (n >= N_NODES) return;
    const float si = isd[n];
    float4 a = z4[(size_t)n * 4 + q];
    float4 acc;
    acc.x = a.x * si * si; acc.y = a.y * si * si;
    acc.z = a.z * si * si; acc.w = a.w * si * si;
    int e = rowptr[n];
    const int end = rowptr[n + 1];
    for (; e + 4 <= end; e += 4) {
        int s0 = csr_src[e],     s1 = csr_src[e + 1];
        int s2 = csr_src[e + 2], s3 = csr_src[e + 3];
        float w0 = isd[s0] * si, w1 = isd[s1] * si;
        float w2 = isd[s2] * si, w3 = isd[s3] * si;
        float4 v0 = z4[(size_t)s0 * 4 + q];
        float4 v1 = z4[(size_t)s1 * 4 + q];
        float4 v2 = z4[(size_t)s2 * 4 + q];
        float4 v3 = z4[(size_t)s3 * 4 + q];
        acc.x += w0 * v0.x; acc.y += w0 * v0.y; acc.z += w0 * v0.z; acc.w += w0 * v0.w;
        acc.x += w1 * v1.x; acc.y += w1 * v1.y; acc.z += w1 * v1.z; acc.w += w1 * v1.w;
        acc.x += w2 * v2.x; acc.y += w2 * v2.y; acc.z += w2 * v2.z; acc.w += w2 * v2.w;
        acc.x += w3 * v3.x; acc.y += w3 * v3.y; acc.z += w3 * v3.z; acc.w += w3 * v3.w;
    }
    for (; e < end; ++e) {
        int s = csr_src[e];
        float w = isd[s] * si;
        float4 v = z4[(size_t)s * 4 + q];
        acc.x += w * v.x; acc.y += w * v.y; acc.z += w * v.z; acc.w += w * v.w;
    }
    out4[(size_t)n * 4 + q] = acc;
}

// ---------------- fallback (round-1 atomic path, all fp32) ----------------

__global__ void k_deg_init(float* __restrict__ deg) {
    int i = blockIdx.x * 256 + threadIdx.x;
    if (i < N_NODES) deg[i] = 1.0f;
}
__global__ void k_deg_count(const int* __restrict__ dst, float* __restrict__ deg, int E) {
    int e = blockIdx.x * 256 + threadIdx.x;
    if (e < E) atomicAdd(&deg[dst[e]], 1.0f);
}
__global__ void k_rsqrt(float* __restrict__ deg) {
    int i = blockIdx.x * 256 + threadIdx.x;
    if (i < N_NODES) deg[i] = rsqrtf(deg[i]);
}
__global__ void k_agg_init(const float4* __restrict__ h, const float* __restrict__ isd,
                           float4* __restrict__ agg) {
    int t = blockIdx.x * 256 + threadIdx.x;
    if (t < N_NODES * (F_HID / 4)) {
        int row = t >> 5;
        float s = isd[row];
        s = s * s;
        float4 v = h[t];
        v.x *= s; v.y *= s; v.z *= s; v.w *= s;
        agg[t] = v;
    }
}
__global__ void k_scatter(const float4* __restrict__ h, const int* __restrict__ src,
                          const int* __restrict__ dst, const float* __restrict__ isd,
                          float* __restrict__ agg, int E) {
    int t = blockIdx.x * 256 + threadIdx.x;
    int e = t >> 5, q = t & 31;
    if (e >= E) return;
    int s = src[e], d = dst[e];
    float norm = isd[s] * isd[d];
    float4 v = h[(long long)s * 32 + q];
    float* out = agg + (long long)d * F_HID + q * 4;
    atomicAdd(out + 0, v.x * norm);
    atomicAdd(out + 1, v.y * norm);
    atomicAdd(out + 2, v.z * norm);
    atomicAdd(out + 3, v.w * norm);
}
template <int BM, int BN, int BK, int TM, int TN, bool RELU_A>
__global__ __launch_bounds__(256) void gemm_nt(const float* __restrict__ A,
                                               const float* __restrict__ B,
                                               float* __restrict__ C,
                                               int M, int N, int K) {
    __shared__ float As[BK][BM + 1];
    __shared__ float Bs[BK][BN + 1];
    const int tid = threadIdx.x;
    const int NTX = BN / TN;
    const int tx = tid % NTX;
    const int ty = tid / NTX;
    const int m0 = blockIdx.x * BM;
    const int n0 = blockIdx.y * BN;
    float acc[TM][TN] = {};
    for (int k0 = 0; k0 < K; k0 += BK) {
        for (int idx = tid; idx < BM * BK; idx += 256) {
            int m = idx / BK, k = idx % BK;
            int gm = m0 + m;
            float v = (gm < M) ? A[(long long)gm * K + k0 + k] : 0.0f;
            if (RELU_A) v = fmaxf(v, 0.0f);
            As[k][m] = v;
        }
        for (int idx = tid; idx < BN * BK; idx += 256) {
            int n = idx / BK, k = idx % BK;
            int gn = n0 + n;
            Bs[k][n] = (gn < N) ? B[(long long)gn * K + k0 + k] : 0.0f;
        }
        __syncthreads();
        for (int k = 0; k < BK; ++k) {
            float a[TM], b[TN];
#pragma unroll
            for (int r = 0; r < TM; ++r) a[r] = As[k][ty * TM + r];
#pragma unroll
            for (int c = 0; c < TN; ++c) b[c] = Bs[k][c * NTX + tx];
#pragma unroll
            for (int r = 0; r < TM; ++r)
#pragma unroll
                for (int c = 0; c < TN; ++c) acc[r][c] += a[r] * b[c];
        }
        __syncthreads();
    }
#pragma unroll
    for (int r = 0; r < TM; ++r) {
        int gm = m0 + ty * TM + r;
        if (gm >= M) continue;
#pragma unroll
        for (int c = 0; c < TN; ++c) {
            int gn = n0 + c * NTX + tx;
            if (gn < N) C[(long long)gm * N + gn] = acc[r][c];
        }
    }
}
__global__ __launch_bounds__(256) void gemm_lin(const float* __restrict__ A,
                                                const float* __restrict__ W,
                                                float* __restrict__ C, int M) {
    __shared__ float Ws[16][129];
    __shared__ float As[16][129];
    const int tid = threadIdx.x;
    for (int idx = tid; idx < 16 * 128; idx += 256) Ws[idx >> 7][idx & 127] = W[idx];
    const int m0 = blockIdx.x * 16;
    for (int idx = tid; idx < 16 * 128; idx += 256) {
        int r = idx >> 7, k = idx & 127;
        int gm = m0 + r;
        As[r][k] = (gm < M) ? A[(long long)gm * 128 + k] : 0.0f;
    }
    __syncthreads();
    const int tc = tid & 15, tr = tid >> 4;
    float s = 0.f;
#pragma unroll 8
    for (int k = 0; k < 128; ++k) s += As[tr][k] * Ws[tc][k];
    int gm = m0 + tr;
    if (gm < M) C[gm * 16 + tc] = s;
}

// ---------------- launcher ----------------

static inline size_t align256(size_t x) { return (x + 255) & ~(size_t)255; }

extern "C" void kernel_launch(void* const* d_in, const int* in_sizes, int n_in,
                              void* d_out, int out_size, void* d_ws, size_t ws_size,
                              hipStream_t stream) {
    const float* x    = (const float*)d_in[0];
    const int*   ei   = (const int*)d_in[1];
    const float* W1   = (const float*)d_in[2];
    const float* W2   = (const float*)d_in[3];
    const float* Wlin = (const float*)d_in[4];
    float* out = (float*)d_out;

    const int E = in_sizes[1] / 2;
    const int* src = ei;
    const int* dst = ei + E;

    // workspace layout
    char* ws = (char*)d_ws;
    size_t off = 0;
    float* isd  = (float*)(ws + off); off += align256((size_t)N_NODES * 4);
    float* Wc   = (float*)(ws + off); off += align256(16 * 128 * 4);
    float* bufA = (float*)(ws + off); off += align256((size_t)N_NODES * F_HID * 4);
    float* bufB = (float*)(ws + off); off += align256((size_t)N_NODES * F_HID * 4);
    int*   hist    = (int*)(ws + off); off += align256((size_t)N_NODES * 4);
    int*   rowptr  = (int*)(ws + off); off += align256(((size_t)N_NODES + 1) * 4);
    int*   blksum  = (int*)(ws + off); off += align256(256 * 4);
    int*   csr_src = (int*)(ws + off); off += align256((size_t)E * 4);
    int*   rank    = (int*)(ws + off); off += align256((size_t)E * 4);
    const bool use_csr = (off <= ws_size);

    const int nblk_nodes = NSCAN_BLKS;
    const int nblk_edges = (E + 255) / 256;
    const int mtiles = (N_NODES + 63) / 64;

    if (use_csr) {
        unsigned* hb = (unsigned*)bufB;   // [N][64] packed bf16x2 (12.8 MB)
        float*    z  = bufA;              // [N][16] fp32

        // 1. CSR build + normalization (one atomic pass)
        hipMemsetAsync(hist, 0, (size_t)N_NODES * 4, stream);
        k_hist_rank<<<nblk_edges, 256, 0, stream>>>(dst, hist, rank, E);
        k_scan_local<<<nblk_nodes, 256, 0, stream>>>(hist, rowptr, blksum);
        k_scan_blk<<<1, 256, 0, stream>>>(blksum);
        k_finalize<<<nblk_nodes, 256, 0, stream>>>(hist, rowptr, blksum, isd, E);
        k_reorder<<<nblk_edges, 256, 0, stream>>>(src, dst, rank, rowptr, csr_src, E);
        // 2. Wc = Wlin @ W2
        k_wc<<<16, 128, 0, stream>>>(W2, Wlin, Wc);
        // 3. h1 = x @ W1^T  -> bf16  (round-8 proven kernel)
        gemm1_db_bf16<<<mtiles, 256, 0, stream>>>(x, W1, hb, N_NODES, F_IN);
        // 4+5. z = relu(A_norm * h1) @ Wc^T   (fused, 2 waves/node)
        k_gather_fused2<<<N_NODES / 2, 256, 0, stream>>>(
            hb, rowptr, csr_src, isd, Wc, z);
        // 6. out = A_norm * z
        k_gather16<<<(N_NODES * 4 + 255) / 256, 256, 0, stream>>>(
            (const float4*)z, rowptr, csr_src, isd, (float4*)out);
    } else {
        // fallback: atomic scatter path (fp32)
        const int nblk_feat = (N_NODES * (F_HID / 4) + 255) / 256;
        const int nblk_scatter = (int)(((long long)E * 32 + 255) / 256);
        k_deg_init<<<(N_NODES + 255) / 256, 256, 0, stream>>>(isd);
        k_deg_count<<<nblk_edges, 256, 0, stream>>>(dst, isd, E);
        k_rsqrt<<<(N_NODES + 255) / 256, 256, 0, stream>>>(isd);
        gemm_nt<64, 128, 20, 4, 8, false>
            <<<dim3(mtiles, 1), 256, 0, stream>>>(x, W1, bufA, N_NODES, F_HID, F_IN);
        k_agg_init<<<nblk_feat, 256, 0, stream>>>((const float4*)bufA, isd, (float4*)bufB);
        k_scatter<<<nblk_scatter, 256, 0, stream>>>((const float4*)bufA, src, dst, isd, bufB, E);
        gemm_nt<64, 128, 16, 4, 8, true>
            <<<dim3(mtiles, 1), 256, 0, stream>>>(bufB, W2, bufA, N_NODES, F_HID, F_HID);
        k_agg_init<<<nblk_feat, 256, 0, stream>>>((const float4*)bufA, isd, (float4*)bufB);
        k_scatter<<<nblk_scatter, 256, 0, stream>>>((const float4*)bufA, src, dst, isd, bufB, E);
        gemm_lin<<<(N_NODES + 15) / 16, 256, 0, stream>>>(bufB, Wlin, out, N_NODES);
    }
}